// Round 2
// baseline (882.470 us; speedup 1.0000x reference)
//
#include <hip/hip_runtime.h>
#include <hip/hip_bf16.h>
#include <cstdint>

#define T_TOKENS 4096
#define DMODEL   1024
#define DHIDDEN  4096
#define NEXP     8
#define GEMM_BLOCKS 1024
#define SLOTS (GEMM_BLOCKS / 8)

typedef __bf16 bf16x8 __attribute__((ext_vector_type(8)));
typedef float  f32x4  __attribute__((ext_vector_type(4)));
typedef unsigned short ushort_t;

// ---------- helpers ----------

__device__ __forceinline__ ushort_t f2bf(float f) {
  union { float f; uint32_t u; } c; c.f = f;
  uint32_t r = c.u + 0x7fffu + ((c.u >> 16) & 1u);   // RNE
  return (ushort_t)(r >> 16);
}

__device__ __forceinline__ void gload_lds16(const void* g, void* l) {
  __builtin_amdgcn_global_load_lds(
      (const __attribute__((address_space(1))) unsigned int*)g,
      (__attribute__((address_space(3))) unsigned int*)l, 16, 0, 0);
}

__device__ __forceinline__ float wave_sum(float v) {
  #pragma unroll
  for (int m = 32; m; m >>= 1) v += __shfl_xor(v, m, 64);
  return v;
}

// ---------- 1. weight convert + transpose: W [E][M][N] f32 -> WT [E][N][M] bf16 ----------

template <int M, int N>
__global__ __launch_bounds__(256)
void convertT_kernel(const float* __restrict__ W, ushort_t* __restrict__ WT) {
  __shared__ float tile[64][65];
  int e  = blockIdx.z;
  int c0 = blockIdx.x * 64;          // N dim
  int r0 = blockIdx.y * 64;          // M dim
  const float* Wp = W + (size_t)e * M * N;
  ushort_t*    Tp = WT + (size_t)e * M * N;
  int t  = threadIdx.x;
  int lr = t >> 4;                   // 0..15
  int lc = (t & 15) * 4;
  #pragma unroll
  for (int i = 0; i < 4; ++i) {
    float4 v = *(const float4*)&Wp[(size_t)(r0 + lr + 16 * i) * N + c0 + lc];
    *(float4*)&tile[lr + 16 * i][lc] = v;
  }
  __syncthreads();
  int sn = t >> 4;                   // n within tile (0..15, +16i)
  int sm = (t & 15) * 4;             // m within tile
  #pragma unroll
  for (int i = 0; i < 4; ++i) {
    int n = sn + 16 * i;
    ushort_t o4[4];
    #pragma unroll
    for (int j = 0; j < 4; ++j) o4[j] = f2bf(tile[sm + j][n]);
    *(uint64_t*)&Tp[(size_t)(c0 + n) * M + r0 + sm] = *(uint64_t*)o4;
  }
}

// ---------- 2. gating: fp32 logits, top-2, softmax, counts ----------

__global__ void gating_kernel(const float* __restrict__ x, const float* __restrict__ Wg,
                              const float* __restrict__ bg, float* __restrict__ logits_out,
                              int* __restrict__ meta, int* __restrict__ ek,
                              float* __restrict__ wk) {
  __shared__ float sWg[DMODEL * NEXP];               // 32 KB
  int tid = threadIdx.x;
  for (int i = tid; i < DMODEL * NEXP; i += 256) sWg[i] = Wg[i];
  __syncthreads();
  int wave = tid >> 6, lane = tid & 63;
  int t = blockIdx.x * 4 + wave;
  const float* xr = x + (size_t)t * DMODEL;
  float a0 = 0, a1 = 0, a2 = 0, a3 = 0, a4 = 0, a5 = 0, a6 = 0, a7 = 0;
  for (int d = lane; d < DMODEL; d += 64) {
    float xv = xr[d];
    const float4* w4 = (const float4*)&sWg[d * 8];
    float4 wa = w4[0], wb = w4[1];
    a0 += xv * wa.x; a1 += xv * wa.y; a2 += xv * wa.z; a3 += xv * wa.w;
    a4 += xv * wb.x; a5 += xv * wb.y; a6 += xv * wb.z; a7 += xv * wb.w;
  }
  a0 = wave_sum(a0); a1 = wave_sum(a1); a2 = wave_sum(a2); a3 = wave_sum(a3);
  a4 = wave_sum(a4); a5 = wave_sum(a5); a6 = wave_sum(a6); a7 = wave_sum(a7);
  if (lane == 0) {
    float lg[NEXP] = {a0 + bg[0], a1 + bg[1], a2 + bg[2], a3 + bg[3],
                      a4 + bg[4], a5 + bg[5], a6 + bg[6], a7 + bg[7]};
    #pragma unroll
    for (int e = 0; e < NEXP; ++e) logits_out[(size_t)t * NEXP + e] = lg[e];
    int i0 = 0; float v0 = lg[0];
    #pragma unroll
    for (int e = 1; e < NEXP; ++e) if (lg[e] > v0) { v0 = lg[e]; i0 = e; }
    int i1 = -1; float v1 = -3.4e38f;
    #pragma unroll
    for (int e = 0; e < NEXP; ++e) if (e != i0 && lg[e] > v1) { v1 = lg[e]; i1 = e; }
    float ex = expf(v1 - v0);
    float w0 = 1.f / (1.f + ex);
    float w1 = ex / (1.f + ex);
    ek[t * 2]     = i0;  ek[t * 2 + 1] = i1;
    wk[t * 2]     = w0;  wk[t * 2 + 1] = w1;
    atomicAdd(&meta[i0], 1);
    atomicAdd(&meta[i1], 1);
  }
}

// ---------- 3. prefix offsets + per-XCD task lists ----------
// meta: [0:8) counts, [8:16) offs, [16:24) scatter cursors, [24] per-XCD ntask1,
// [25] per-XCD ntask2, [32:40) GEMM1 queue cursors, [40:48) GEMM2 queue cursors.
// Task = (e<<12)|(kh<<11)|(rt<<5)|ct.
// GEMM1: XCD x owns ct with ct%8==x (4 per expert); list order (e, ct, rt).
// GEMM2: XCD x owns ct==x; K split in half (kh); list order (e, kh, rt).

__global__ void offsets_kernel(int* __restrict__ meta, int* __restrict__ tasks1,
                               int* __restrict__ tasks2) {
  __shared__ int snrt[NEXP], spsum[NEXP + 1];
  int tid = threadIdx.x;
  if (tid == 0) {
    int s = 0, p = 0;
    for (int e = 0; e < NEXP; ++e) {
      meta[8 + e] = s;
      int cnt = meta[e];
      s += cnt;
      int n = (cnt + 127) >> 7;
      snrt[e] = n;
      spsum[e] = p; p += n;
    }
    spsum[NEXP] = p;
    meta[24] = 4 * p;                 // tasks per XCD, GEMM1
    meta[25] = 2 * p;                 // tasks per XCD, GEMM2
  }
  __syncthreads();
  {
    int x = tid >> 5, e = (tid >> 2) & 7, ci = tid & 3;   // 256 threads
    int n = snrt[e];
    int ct = ci * 8 + x;
    int base = x * 512 + 4 * spsum[e] + ci * n;
    for (int r = 0; r < n; ++r) tasks1[base + r] = (e << 12) | (r << 5) | ct;
  }
  if (tid < 128) {
    int x = tid >> 4, e = (tid >> 1) & 7, kh = tid & 1;   // 128 threads
    int n = snrt[e];
    int base = x * 256 + 2 * spsum[e] + kh * n;
    for (int r = 0; r < n; ++r) tasks2[base + r] = (e << 12) | (kh << 11) | (r << 5) | x;
  }
}

// ---------- 4. scatter/gather: x rows -> bf16 Xg in expert-segment order ----------

__global__ void scatter_kernel(const float* __restrict__ x, const int* __restrict__ ek,
                               int* __restrict__ meta, int* __restrict__ inv,
                               ushort_t* __restrict__ Xg) {
  int b = blockIdx.x;                // 0..2T-1
  int t = b >> 1, k = b & 1;
  __shared__ int spos;
  if (threadIdx.x == 0) {
    int e   = ek[t * 2 + k];
    int pos = meta[8 + e] + atomicAdd(&meta[16 + e], 1);
    inv[t * 2 + k] = pos;
    spos = pos;
  }
  __syncthreads();
  int pos = spos;
  float4 v = ((const float4*)(x + (size_t)t * DMODEL))[threadIdx.x];
  ushort_t* dst = Xg + (size_t)pos * DMODEL + threadIdx.x * 4;
  dst[0] = f2bf(v.x); dst[1] = f2bf(v.y); dst[2] = f2bf(v.z); dst[3] = f2bf(v.w);
}

// ---------- 5. persistent grouped GEMM, dynamic per-XCD work queue + stealing ----
// Each block pulls tasks from its own XCD's queue (cursor meta[curBase+x]) via
// atomicAdd from lane 0 (broadcast through LDS). Consecutive pulls share the
// same B panel (list order (e,ct,rt)) -> L2-resident per XCD. When the own
// queue is drained, steal from the other XCDs' queues -> tail shrinks from
// ceil(ntask/slots)*tau to ~mean + tau.

template <int KTOT, int NTOT, bool FUSE, int KSPLIT>
__global__ __launch_bounds__(256, 2)
void moe_gemm(const ushort_t* __restrict__ A, const ushort_t* __restrict__ BT,
              int* __restrict__ meta, const int* __restrict__ tasks,
              int ntask_slot, int curBase, int tstride, const float* __restrict__ bias,
              ushort_t* __restrict__ outb, float* __restrict__ outf0,
              float* __restrict__ outf1) {
  int nloc = meta[ntask_slot];
  int x    = blockIdx.x & 7;

  __shared__ __align__(16) ushort_t lA[128 * 64];    // 16 KB
  __shared__ __align__(16) ushort_t lB[128 * 64];    // 16 KB
  __shared__ int sTask;

  int tid  = threadIdx.x;
  int wave = tid >> 6, lane = tid & 63;
  int wr = wave >> 1, wc = wave & 1;
  int srow = tid >> 3;      // 0..31
  int sblk = tid & 7;       // 16B block within a 128B row
  int quad = lane >> 4, m16 = lane & 15;
  constexpr int KLEN = KTOT / KSPLIT;

  int vq = 0, vx = x;       // victim queue state (only thread 0 advances it)

  for (;;) {
    if (tid == 0) {
      int task = -1;
      while (vq < 8) {
        int ti = atomicAdd(&meta[curBase + vx], 1);
        if (ti < nloc) { task = tasks[vx * tstride + ti]; break; }
        ++vq; vx = (x + vq) & 7;
      }
      sTask = task;
    }
    __syncthreads();
    int task = sTask;
    __syncthreads();
    if (task < 0) break;

    int e  = task >> 12;
    int kh = (task >> 11) & 1;
    int rt = (task >> 5) & 63;
    int ct = task & 31;
    int cnt     = meta[e];
    int rowBase = meta[8 + e] + rt * 128;
    int n0      = ct * 128;
    int kbeg    = kh * KLEN;

    const ushort_t* Ag = A + (size_t)rowBase * KTOT;
    const ushort_t* Bg = BT + (size_t)e * NTOT * KTOT + (size_t)n0 * KTOT;

    f32x4 acc[4][4];
    #pragma unroll
    for (int i = 0; i < 4; ++i)
      #pragma unroll
      for (int j = 0; j < 4; ++j) acc[i][j] = (f32x4){0.f, 0.f, 0.f, 0.f};

    for (int k0 = kbeg; k0 < kbeg + KLEN; k0 += 64) {
      #pragma unroll
      for (int r = 0; r < 4; ++r) {
        int row  = r * 32 + srow;
        int gblk = sblk ^ (row & 7);                  // XOR bank swizzle (source side)
        gload_lds16(Ag + (size_t)row * KTOT + k0 + gblk * 8,
                    (char*)lA + r * 4096 + wave * 1024);
        gload_lds16(Bg + (size_t)row * KTOT + k0 + gblk * 8,
                    (char*)lB + r * 4096 + wave * 1024);
      }
      __syncthreads();
      #pragma unroll
      for (int kk = 0; kk < 64; kk += 32) {
        int bblk = (kk >> 3) + quad;                  // global 16B block idx 0..7
        bf16x8 af[4], bff[4];
        #pragma unroll
        for (int i = 0; i < 4; ++i) {
          int row = wr * 64 + i * 16 + m16;
          af[i] = *(const bf16x8*)&lA[row * 64 + ((bblk ^ (row & 7)) << 3)];
        }
        #pragma unroll
        for (int j = 0; j < 4; ++j) {
          int nrow = wc * 64 + j * 16 + m16;
          bff[j] = *(const bf16x8*)&lB[nrow * 64 + ((bblk ^ (nrow & 7)) << 3)];
        }
        #pragma unroll
        for (int i = 0; i < 4; ++i)
          #pragma unroll
          for (int j = 0; j < 4; ++j)
            acc[i][j] = __builtin_amdgcn_mfma_f32_16x16x32_bf16(af[i], bff[j], acc[i][j], 0, 0, 0);
      }
      __syncthreads();
    }

    // epilogue: D row = (lane>>4)*4 + reg, col = lane&15 (verified m89/m91)
    float* outf = kh ? outf1 : outf0;
    #pragma unroll
    for (int i = 0; i < 4; ++i) {
      #pragma unroll
      for (int j = 0; j < 4; ++j) {
        int col = n0 + wc * 64 + j * 16 + m16;
        #pragma unroll
        for (int r = 0; r < 4; ++r) {
          int rowIn = wr * 64 + i * 16 + quad * 4 + r;
          if (rt * 128 + rowIn < cnt) {
            size_t grow = (size_t)(rowBase + rowIn);
            float v = acc[i][j][r];
            if (FUSE) {
              v += bias[e * NTOT + col];
              v = fmaxf(v, 0.f);
              outb[grow * NTOT + col] = f2bf(v);
            } else {
              outf[grow * NTOT + col] = v;
            }
          }
        }
      }
    }
  }
}

// ---------- 6. combine: out[t] = sum_k wk*(yA[pk]+yB[pk]+b2[ek]) ----------

__global__ void combine_kernel(const float* __restrict__ yA, const float* __restrict__ yB,
                               const int* __restrict__ inv, const int* __restrict__ ek,
                               const float* __restrict__ wk, const float* __restrict__ b2,
                               float* __restrict__ out) {
  int t = blockIdx.x;
  int d = threadIdx.x * 4;
  int p0 = inv[t * 2], p1 = inv[t * 2 + 1];
  int e0 = ek[t * 2],  e1 = ek[t * 2 + 1];
  float w0 = wk[t * 2], w1 = wk[t * 2 + 1];
  float4 a0 = *(const float4*)&yA[(size_t)p0 * DMODEL + d];
  float4 b0 = *(const float4*)&yB[(size_t)p0 * DMODEL + d];
  float4 a1 = *(const float4*)&yA[(size_t)p1 * DMODEL + d];
  float4 b1 = *(const float4*)&yB[(size_t)p1 * DMODEL + d];
  float4 q0 = *(const float4*)&b2[(size_t)e0 * DMODEL + d];
  float4 q1 = *(const float4*)&b2[(size_t)e1 * DMODEL + d];
  float4 o;
  o.x = w0 * (a0.x + b0.x + q0.x) + w1 * (a1.x + b1.x + q1.x);
  o.y = w0 * (a0.y + b0.y + q0.y) + w1 * (a1.y + b1.y + q1.y);
  o.z = w0 * (a0.z + b0.z + q0.z) + w1 * (a1.z + b1.z + q1.z);
  o.w = w0 * (a0.w + b0.w + q0.w) + w1 * (a1.w + b1.w + q1.w);
  *(float4*)&out[(size_t)t * DMODEL + d] = o;
}

// ---------- launch ----------

extern "C" void kernel_launch(void* const* d_in, const int* in_sizes, int n_in,
                              void* d_out, int out_size, void* d_ws, size_t ws_size,
                              hipStream_t stream) {
  const float* x  = (const float*)d_in[0];
  const float* Wg = (const float*)d_in[1];
  const float* bg = (const float*)d_in[2];
  const float* W1 = (const float*)d_in[3];
  const float* b1 = (const float*)d_in[4];
  const float* W2 = (const float*)d_in[5];
  const float* b2 = (const float*)d_in[6];
  float* out    = (float*)d_out;
  float* logits = out + (size_t)T_TOKENS * DMODEL;

  char* ws = (char*)d_ws;
  size_t off = 0;
  auto alloc = [&](size_t b) { size_t r = off; off += (b + 255) & ~(size_t)255; return r; };
  ushort_t* W1T  = (ushort_t*)(ws + alloc((size_t)NEXP * DMODEL * DHIDDEN * 2)); // 67.1 MB
  ushort_t* W2T  = (ushort_t*)(ws + alloc((size_t)NEXP * DMODEL * DHIDDEN * 2)); // 67.1 MB
  ushort_t* Xg   = (ushort_t*)(ws + alloc((size_t)(2 * T_TOKENS + 128) * DMODEL * 2));   // 17.0 MB
  ushort_t* hbuf = (ushort_t*)(ws + alloc((size_t)(2 * T_TOKENS + 128) * DHIDDEN * 2));  // 68.2 MB
  float*    ybuf = (float*)(ws + alloc((size_t)(2 * T_TOKENS + 128) * DMODEL * 4));      // 34.1 MB
  int*      meta = (int*)(ws + alloc(4096));
  int*      ek   = (int*)(ws + alloc((size_t)T_TOKENS * 2 * 4));
  float*    wk   = (float*)(ws + alloc((size_t)T_TOKENS * 2 * 4));
  int*      inv  = (int*)(ws + alloc((size_t)T_TOKENS * 2 * 4));
  int*      tk1  = (int*)(ws + alloc(8 * 512 * 4));  // per-XCD GEMM1 lists
  int*      tk2  = (int*)(ws + alloc(8 * 256 * 4));  // per-XCD GEMM2 lists
  // GEMM2 second K-half partials alias W1T (dead after GEMM1): 33.6 < 67.1 MB
  float*    ybufB = (float*)W1T;
  (void)ws_size; (void)in_sizes; (void)n_in; (void)out_size;

  hipMemsetAsync(meta, 0, 256, stream);

  convertT_kernel<DMODEL, DHIDDEN>
      <<<dim3(DHIDDEN / 64, DMODEL / 64, NEXP), 256, 0, stream>>>(W1, W1T);
  convertT_kernel<DHIDDEN, DMODEL>
      <<<dim3(DMODEL / 64, DHIDDEN / 64, NEXP), 256, 0, stream>>>(W2, W2T);

  gating_kernel<<<T_TOKENS / 4, 256, 0, stream>>>(x, Wg, bg, logits, meta, ek, wk);
  offsets_kernel<<<1, 256, 0, stream>>>(meta, tk1, tk2);
  scatter_kernel<<<T_TOKENS * 2, 256, 0, stream>>>(x, ek, meta, inv, Xg);

  moe_gemm<DMODEL, DHIDDEN, true, 1>
      <<<GEMM_BLOCKS, 256, 0, stream>>>(Xg, W1T, meta, tk1, 24, 32, 512, b1, hbuf, nullptr, nullptr);
  moe_gemm<DHIDDEN, DMODEL, false, 2>
      <<<GEMM_BLOCKS, 256, 0, stream>>>(hbuf, W2T, meta, tk2, 25, 40, 256, nullptr, nullptr, ybuf, ybufB);

  combine_kernel<<<T_TOKENS, 256, 0, stream>>>(ybuf, ybufB, inv, ek, wk, b2, out);
}

// Round 3
// 580.684 us; speedup vs baseline: 1.5197x; 1.5197x over previous
//
#include <hip/hip_runtime.h>
#include <hip/hip_bf16.h>
#include <cstdint>

#define T_TOKENS 4096
#define DMODEL   1024
#define DHIDDEN  4096
#define NEXP     8
#define MAXT1    288     // per-XCD GEMM1 task-list stride (4 * max p = 4*72)
#define MAXT2    144     // per-XCD GEMM2 task-list stride (2 * max p)

typedef __bf16 bf16x8 __attribute__((ext_vector_type(8)));
typedef float  f32x4  __attribute__((ext_vector_type(4)));
typedef unsigned short ushort_t;

// ---------- helpers ----------

__device__ __forceinline__ ushort_t f2bf(float f) {
  union { float f; uint32_t u; } c; c.f = f;
  uint32_t r = c.u + 0x7fffu + ((c.u >> 16) & 1u);   // RNE
  return (ushort_t)(r >> 16);
}

__device__ __forceinline__ void gload_lds16(const void* g, void* l) {
  __builtin_amdgcn_global_load_lds(
      (const __attribute__((address_space(1))) unsigned int*)g,
      (__attribute__((address_space(3))) unsigned int*)l, 16, 0, 0);
}

__device__ __forceinline__ float wave_sum(float v) {
  #pragma unroll
  for (int m = 32; m; m >>= 1) v += __shfl_xor(v, m, 64);
  return v;
}

// ---------- 1. fused weight convert+transpose: W1 and W2 in one launch ----------
// z<8: W1 expert z ([DMODEL][DHIDDEN] -> [DHIDDEN][DMODEL] bf16)
// z>=8: W2 expert z-8 ([DHIDDEN][DMODEL] -> [DMODEL][DHIDDEN] bf16), grid remapped.

__global__ __launch_bounds__(256)
void convert_both(const float* __restrict__ W1, const float* __restrict__ W2,
                  ushort_t* __restrict__ W1T, ushort_t* __restrict__ W2T) {
  __shared__ float tile[64][65];
  int z = blockIdx.z;
  const float* W; ushort_t* WT; int M, N, c0, r0, e;
  if (z < 8) {
    W = W1; WT = W1T; M = DMODEL; N = DHIDDEN; e = z;
    c0 = blockIdx.x * 64; r0 = blockIdx.y * 64;
  } else {
    W = W2; WT = W2T; M = DHIDDEN; N = DMODEL; e = z - 8;
    c0 = (blockIdx.x & 15) * 64;
    r0 = (blockIdx.y * 4 + (blockIdx.x >> 4)) * 64;
  }
  const float* Wp = W + (size_t)e * M * N;
  ushort_t*    Tp = WT + (size_t)e * M * N;
  int t  = threadIdx.x;
  int lr = t >> 4;                   // 0..15
  int lc = (t & 15) * 4;
  #pragma unroll
  for (int i = 0; i < 4; ++i) {
    float4 v = *(const float4*)&Wp[(size_t)(r0 + lr + 16 * i) * N + c0 + lc];
    *(float4*)&tile[lr + 16 * i][lc] = v;
  }
  __syncthreads();
  int sn = t >> 4;
  int sm = (t & 15) * 4;
  #pragma unroll
  for (int i = 0; i < 4; ++i) {
    int n = sn + 16 * i;
    ushort_t o4[4];
    #pragma unroll
    for (int j = 0; j < 4; ++j) o4[j] = f2bf(tile[sm + j][n]);
    *(uint64_t*)&Tp[(size_t)(c0 + n) * M + r0 + sm] = *(uint64_t*)o4;
  }
}

// ---------- 2. gating: fp32 logits, top-2, softmax — NO global atomics ----------

__global__ void gating_kernel(const float* __restrict__ x, const float* __restrict__ Wg,
                              const float* __restrict__ bg, float* __restrict__ logits_out,
                              int* __restrict__ ek, float* __restrict__ wk) {
  __shared__ float sWg[DMODEL * NEXP];               // 32 KB
  int tid = threadIdx.x;
  for (int i = tid; i < DMODEL * NEXP; i += 256) sWg[i] = Wg[i];
  __syncthreads();
  int wave = tid >> 6, lane = tid & 63;
  int t = blockIdx.x * 4 + wave;
  const float* xr = x + (size_t)t * DMODEL;
  float a0 = 0, a1 = 0, a2 = 0, a3 = 0, a4 = 0, a5 = 0, a6 = 0, a7 = 0;
  for (int d = lane; d < DMODEL; d += 64) {
    float xv = xr[d];
    const float4* w4 = (const float4*)&sWg[d * 8];
    float4 wa = w4[0], wb = w4[1];
    a0 += xv * wa.x; a1 += xv * wa.y; a2 += xv * wa.z; a3 += xv * wa.w;
    a4 += xv * wb.x; a5 += xv * wb.y; a6 += xv * wb.z; a7 += xv * wb.w;
  }
  a0 = wave_sum(a0); a1 = wave_sum(a1); a2 = wave_sum(a2); a3 = wave_sum(a3);
  a4 = wave_sum(a4); a5 = wave_sum(a5); a6 = wave_sum(a6); a7 = wave_sum(a7);
  if (lane == 0) {
    float lg[NEXP] = {a0 + bg[0], a1 + bg[1], a2 + bg[2], a3 + bg[3],
                      a4 + bg[4], a5 + bg[5], a6 + bg[6], a7 + bg[7]};
    #pragma unroll
    for (int e = 0; e < NEXP; ++e) logits_out[(size_t)t * NEXP + e] = lg[e];
    int i0 = 0; float v0 = lg[0];
    #pragma unroll
    for (int e = 1; e < NEXP; ++e) if (lg[e] > v0) { v0 = lg[e]; i0 = e; }
    int i1 = -1; float v1 = -3.4e38f;
    #pragma unroll
    for (int e = 0; e < NEXP; ++e) if (e != i0 && lg[e] > v1) { v1 = lg[e]; i1 = e; }
    float ex = expf(v1 - v0);
    float w0 = 1.f / (1.f + ex);
    float w1 = ex / (1.f + ex);
    ek[t * 2]     = i0;  ek[t * 2 + 1] = i1;
    wk[t * 2]     = w0;  wk[t * 2 + 1] = w1;
  }
}

// ---------- 3. plan: counts, offsets, deterministic scatter ranks, task lists ----
// One block, 256 threads, zero global atomics. Each thread owns 32 routing slots;
// per-expert counts bit-packed in a uint64 (<=32 per chunk fits 8 bits) to avoid
// runtime-indexed register arrays (scratch, rule #20). Chunk-exclusive prefix via
// 8 serial scans (threads 0..7). meta: [0:8) counts, [8:16) offs, [24] ntask1/XCD,
// [25] ntask2/XCD. Task = (e<<12)|(kh<<11)|(rt<<5)|ct.

__global__ __launch_bounds__(256)
void plan_kernel(const int* __restrict__ ek, int* __restrict__ meta,
                 int* __restrict__ inv, int* __restrict__ tasks1,
                 int* __restrict__ tasks2) {
  __shared__ int part[256][NEXP];                    // 8 KB
  __shared__ int offs[NEXP], snrt[NEXP], spsum[NEXP];
  int tid  = threadIdx.x;
  int base = tid * 32;
  uint64_t c64 = 0;
  #pragma unroll
  for (int s = 0; s < 32; ++s) c64 += 1ull << (8 * ek[base + s]);
  #pragma unroll
  for (int e = 0; e < NEXP; ++e) part[tid][e] = (int)((c64 >> (8 * e)) & 255);
  __syncthreads();
  if (tid < NEXP) {                                  // exclusive scan over 256 chunks
    int s = 0;
    for (int c = 0; c < 256; ++c) { int v = part[c][tid]; part[c][tid] = s; s += v; }
    meta[tid] = s;                                   // per-expert count
  }
  __syncthreads();
  if (tid == 0) {
    int s = 0, p = 0;
    for (int e = 0; e < NEXP; ++e) {
      int cnt = meta[e];
      meta[8 + e] = s; offs[e] = s; s += cnt;
      int n = (cnt + 127) >> 7;
      snrt[e] = n; spsum[e] = p; p += n;
    }
    meta[24] = 4 * p;                                // tasks per XCD, GEMM1
    meta[25] = 2 * p;                                // tasks per XCD, GEMM2
  }
  __syncthreads();
  #pragma unroll
  for (int e = 0; e < NEXP; ++e) part[tid][e] += offs[e];  // own row only
  c64 = 0;
  for (int s = 0; s < 32; ++s) {                     // deterministic ranks
    int e = ek[base + s];
    inv[base + s] = part[tid][e] + (int)((c64 >> (8 * e)) & 255);
    c64 += 1ull << (8 * e);
  }
  {                                                  // GEMM1 list: (e, ct, rt) per XCD
    int x = tid >> 5, e = (tid >> 2) & 7, ci = tid & 3;
    int n = snrt[e], ct = ci * 8 + x;
    int b1 = x * MAXT1 + 4 * spsum[e] + ci * n;
    for (int r = 0; r < n; ++r) tasks1[b1 + r] = (e << 12) | (r << 5) | ct;
  }
  if (tid < 128) {                                   // GEMM2 list: (e, kh, rt), ct = x
    int x = tid >> 4, e = (tid >> 1) & 7, kh = tid & 1;
    int n = snrt[e];
    int b2 = x * MAXT2 + 2 * spsum[e] + kh * n;
    for (int r = 0; r < n; ++r) tasks2[b2 + r] = (e << 12) | (kh << 11) | (r << 5) | x;
  }
}

// ---------- 4. scatter: pure copy via precomputed ranks (no atomics) ----------

__global__ void scatter_kernel(const float* __restrict__ x, const int* __restrict__ inv,
                               ushort_t* __restrict__ Xg) {
  int b = blockIdx.x;                // routing slot 0..2T-1
  int t = b >> 1;
  int pos = inv[b];                  // wave-uniform scalar load
  float4 v = ((const float4*)(x + (size_t)t * DMODEL))[threadIdx.x];
  ushort_t* dst = Xg + (size_t)pos * DMODEL + threadIdx.x * 4;
  dst[0] = f2bf(v.x); dst[1] = f2bf(v.y); dst[2] = f2bf(v.z); dst[3] = f2bf(v.w);
}

// ---------- 5. grouped GEMM: one task per block, HW-backfill scheduling ----------
// R0's verified inner loop. Grid = 8 * MAXT (padded); blocks past the real task
// count exit immediately and free their slot — the HW dispatcher is the work
// queue, no atomics, no ceil-quantized static rounds. b&7 == XCD for the first
// dispatch wave -> per-XCD (e,ct,rt) list order keeps B panels L2-local.

template <int KTOT, int NTOT, bool FUSE, int KSPLIT>
__global__ __launch_bounds__(256, 4)
void moe_gemm(const ushort_t* __restrict__ A, const ushort_t* __restrict__ BT,
              const int* __restrict__ meta, const int* __restrict__ tasks,
              int ntask_slot, int tstride, const float* __restrict__ bias,
              ushort_t* __restrict__ outb, float* __restrict__ outf0,
              float* __restrict__ outf1) {
  int x = blockIdx.x & 7;
  int i = blockIdx.x >> 3;
  if (i >= meta[ntask_slot]) return;
  int task = tasks[x * tstride + i];

  __shared__ __align__(16) ushort_t lA[128 * 64];    // 16 KB
  __shared__ __align__(16) ushort_t lB[128 * 64];    // 16 KB

  int tid  = threadIdx.x;
  int wave = tid >> 6, lane = tid & 63;
  int wr = wave >> 1, wc = wave & 1;
  int srow = tid >> 3;      // 0..31
  int sblk = tid & 7;       // 16B block within a 128B row
  int quad = lane >> 4, m16 = lane & 15;
  constexpr int KLEN = KTOT / KSPLIT;

  int e  = task >> 12;
  int kh = (task >> 11) & 1;
  int rt = (task >> 5) & 63;
  int ct = task & 31;
  int cnt     = meta[e];
  int rowBase = meta[8 + e] + rt * 128;
  int n0      = ct * 128;
  int kbeg    = kh * KLEN;

  const ushort_t* Ag = A + (size_t)rowBase * KTOT;
  const ushort_t* Bg = BT + (size_t)e * NTOT * KTOT + (size_t)n0 * KTOT;

  f32x4 acc[4][4];
  #pragma unroll
  for (int i2 = 0; i2 < 4; ++i2)
    #pragma unroll
    for (int j = 0; j < 4; ++j) acc[i2][j] = (f32x4){0.f, 0.f, 0.f, 0.f};

  for (int k0 = kbeg; k0 < kbeg + KLEN; k0 += 64) {
    #pragma unroll
    for (int r = 0; r < 4; ++r) {
      int row  = r * 32 + srow;
      int gblk = sblk ^ (row & 7);                  // XOR bank swizzle (source side)
      gload_lds16(Ag + (size_t)row * KTOT + k0 + gblk * 8,
                  (char*)lA + r * 4096 + wave * 1024);
      gload_lds16(Bg + (size_t)row * KTOT + k0 + gblk * 8,
                  (char*)lB + r * 4096 + wave * 1024);
    }
    __syncthreads();
    #pragma unroll
    for (int kk = 0; kk < 64; kk += 32) {
      int bblk = (kk >> 3) + quad;                  // global 16B block idx 0..7
      bf16x8 af[4], bff[4];
      #pragma unroll
      for (int i2 = 0; i2 < 4; ++i2) {
        int row = wr * 64 + i2 * 16 + m16;
        af[i2] = *(const bf16x8*)&lA[row * 64 + ((bblk ^ (row & 7)) << 3)];
      }
      #pragma unroll
      for (int j = 0; j < 4; ++j) {
        int nrow = wc * 64 + j * 16 + m16;
        bff[j] = *(const bf16x8*)&lB[nrow * 64 + ((bblk ^ (nrow & 7)) << 3)];
      }
      #pragma unroll
      for (int i2 = 0; i2 < 4; ++i2)
        #pragma unroll
        for (int j = 0; j < 4; ++j)
          acc[i2][j] = __builtin_amdgcn_mfma_f32_16x16x32_bf16(af[i2], bff[j], acc[i2][j], 0, 0, 0);
    }
    __syncthreads();
  }

  // epilogue: D row = (lane>>4)*4 + reg, col = lane&15 (verified m89/m91)
  float* outf = kh ? outf1 : outf0;
  #pragma unroll
  for (int i2 = 0; i2 < 4; ++i2) {
    #pragma unroll
    for (int j = 0; j < 4; ++j) {
      int col = n0 + wc * 64 + j * 16 + m16;
      #pragma unroll
      for (int r = 0; r < 4; ++r) {
        int rowIn = wr * 64 + i2 * 16 + quad * 4 + r;
        if (rt * 128 + rowIn < cnt) {
          size_t grow = (size_t)(rowBase + rowIn);
          float v = acc[i2][j][r];
          if (FUSE) {
            v += bias[e * NTOT + col];
            v = fmaxf(v, 0.f);
            outb[grow * NTOT + col] = f2bf(v);
          } else {
            outf[grow * NTOT + col] = v;
          }
        }
      }
    }
  }
}

// ---------- 6. combine: out[t] = sum_k wk*(yA[pk]+yB[pk]+b2[ek]) ----------

__global__ void combine_kernel(const float* __restrict__ yA, const float* __restrict__ yB,
                               const int* __restrict__ inv, const int* __restrict__ ek,
                               const float* __restrict__ wk, const float* __restrict__ b2,
                               float* __restrict__ out) {
  int t = blockIdx.x;
  int d = threadIdx.x * 4;
  int p0 = inv[t * 2], p1 = inv[t * 2 + 1];
  int e0 = ek[t * 2],  e1 = ek[t * 2 + 1];
  float w0 = wk[t * 2], w1 = wk[t * 2 + 1];
  float4 a0 = *(const float4*)&yA[(size_t)p0 * DMODEL + d];
  float4 b0 = *(const float4*)&yB[(size_t)p0 * DMODEL + d];
  float4 a1 = *(const float4*)&yA[(size_t)p1 * DMODEL + d];
  float4 b1 = *(const float4*)&yB[(size_t)p1 * DMODEL + d];
  float4 q0 = *(const float4*)&b2[(size_t)e0 * DMODEL + d];
  float4 q1 = *(const float4*)&b2[(size_t)e1 * DMODEL + d];
  float4 o;
  o.x = w0 * (a0.x + b0.x + q0.x) + w1 * (a1.x + b1.x + q1.x);
  o.y = w0 * (a0.y + b0.y + q0.y) + w1 * (a1.y + b1.y + q1.y);
  o.z = w0 * (a0.z + b0.z + q0.z) + w1 * (a1.z + b1.z + q1.z);
  o.w = w0 * (a0.w + b0.w + q0.w) + w1 * (a1.w + b1.w + q1.w);
  *(float4*)&out[(size_t)t * DMODEL + d] = o;
}

// ---------- launch ----------

extern "C" void kernel_launch(void* const* d_in, const int* in_sizes, int n_in,
                              void* d_out, int out_size, void* d_ws, size_t ws_size,
                              hipStream_t stream) {
  const float* x  = (const float*)d_in[0];
  const float* Wg = (const float*)d_in[1];
  const float* bg = (const float*)d_in[2];
  const float* W1 = (const float*)d_in[3];
  const float* b1 = (const float*)d_in[4];
  const float* W2 = (const float*)d_in[5];
  const float* b2 = (const float*)d_in[6];
  float* out    = (float*)d_out;
  float* logits = out + (size_t)T_TOKENS * DMODEL;

  char* ws = (char*)d_ws;
  size_t off = 0;
  auto alloc = [&](size_t b) { size_t r = off; off += (b + 255) & ~(size_t)255; return r; };
  ushort_t* W1T  = (ushort_t*)(ws + alloc((size_t)NEXP * DMODEL * DHIDDEN * 2)); // 67.1 MB
  ushort_t* W2T  = (ushort_t*)(ws + alloc((size_t)NEXP * DMODEL * DHIDDEN * 2)); // 67.1 MB
  ushort_t* Xg   = (ushort_t*)(ws + alloc((size_t)(2 * T_TOKENS + 128) * DMODEL * 2));   // 17.0 MB
  ushort_t* hbuf = (ushort_t*)(ws + alloc((size_t)(2 * T_TOKENS + 128) * DHIDDEN * 2));  // 68.2 MB
  float*    ybuf = (float*)(ws + alloc((size_t)(2 * T_TOKENS + 128) * DMODEL * 4));      // 34.1 MB
  int*      meta = (int*)(ws + alloc(4096));
  int*      ek   = (int*)(ws + alloc((size_t)T_TOKENS * 2 * 4));
  float*    wk   = (float*)(ws + alloc((size_t)T_TOKENS * 2 * 4));
  int*      inv  = (int*)(ws + alloc((size_t)T_TOKENS * 2 * 4));
  int*      tk1  = (int*)(ws + alloc(8 * MAXT1 * 4));
  int*      tk2  = (int*)(ws + alloc(8 * MAXT2 * 4));
  // GEMM2 second K-half partials alias W1T (dead after GEMM1): 33.6 < 67.1 MB
  float*    ybufB = (float*)W1T;
  (void)ws_size; (void)in_sizes; (void)n_in; (void)out_size;

  convert_both<<<dim3(64, 16, 16), 256, 0, stream>>>(W1, W2, W1T, W2T);

  gating_kernel<<<T_TOKENS / 4, 256, 0, stream>>>(x, Wg, bg, logits, ek, wk);
  plan_kernel<<<1, 256, 0, stream>>>(ek, meta, inv, tk1, tk2);
  scatter_kernel<<<T_TOKENS * 2, 256, 0, stream>>>(x, inv, Xg);

  moe_gemm<DMODEL, DHIDDEN, true, 1>
      <<<8 * MAXT1, 256, 0, stream>>>(Xg, W1T, meta, tk1, 24, MAXT1, b1, hbuf, nullptr, nullptr);
  moe_gemm<DHIDDEN, DMODEL, false, 2>
      <<<8 * MAXT2, 256, 0, stream>>>(hbuf, W2T, meta, tk2, 25, MAXT2, nullptr, nullptr, ybuf, ybufB);

  combine_kernel<<<T_TOKENS, 256, 0, stream>>>(ybuf, ybufB, inv, ek, wk, b2, out);
}